// Round 18
// baseline (65.383 us; speedup 1.0000x reference)
//
#include <hip/hip_runtime.h>
#include <hip/hip_bf16.h>
#include <cstdint>

#define FLT 32
#define TOUT 505
#define TT 2048
#define MROWS 16384
#define QROWS 4040                 // 8*505
#define KDIM 512
#define BK 64
#define NT 8                       // KDIM/BK

typedef float f32x4 __attribute__((ext_vector_type(4)));
typedef __bf16 bf16x8 __attribute__((ext_vector_type(8)));

static __device__ __forceinline__ ushort f2bf(float f) {
  uint32_t u = __float_as_uint(f);
  uint32_t r = (u + 0x7fffu + ((u >> 16) & 1u)) >> 16;
  return (ushort)r;
}
static __device__ __forceinline__ float bf2f(ushort h) {
  return __uint_as_float(((uint32_t)h) << 16);
}
// native casts -> compiler emits v_cvt_pk_bf16_f32 (RNE; verified R14: absmax unchanged)
static __device__ __forceinline__ bf16x8 cvt8(const float4& lo, const float4& hi) {
  bf16x8 v;
  v[0] = (__bf16)lo.x; v[1] = (__bf16)lo.y; v[2] = (__bf16)lo.z; v[3] = (__bf16)lo.w;
  v[4] = (__bf16)hi.x; v[5] = (__bf16)hi.y; v[6] = (__bf16)hi.z; v[7] = (__bf16)hi.w;
  return v;
}

// ---- wprep: W transposes (192 blocks) + bias gather (1 block). No x pass. --
__global__ void wprep_kernel(const float* __restrict__ Wq, const float* __restrict__ Wk,
                             const float* __restrict__ Wv, const float* __restrict__ bq,
                             const float* __restrict__ bk, const float* __restrict__ bv,
                             ushort* __restrict__ wt, float* __restrict__ bias) {
  const int bid = blockIdx.x;
  const int tid = threadIdx.x;
  if (bid < 192) {                        // 64x64 transpose tiles, 3 matrices
    __shared__ ushort lds[64][66];        // 132B stride: conflict-free
    int mat = bid >> 6;                   // 0 Wq, 1 Wk, 2 Wv
    int w = bid & 63;
    int k0 = (w >> 3) * 64, n0 = (w & 7) * 64;
    const float* W = (mat == 0) ? Wq : (mat == 1) ? Wk : Wv;
    int nn = tid & 63;
    #pragma unroll
    for (int r = 0; r < 16; ++r) {
      int kk = r * 4 + (tid >> 6);
      lds[kk][nn] = f2bf(W[(size_t)(k0 + kk) * 512 + n0 + nn]);   // coalesced
    }
    __syncthreads();
    int kk2 = tid & 63;
    #pragma unroll
    for (int r = 0; r < 16; ++r) {
      int nn2 = r * 4 + (tid >> 6);
      wt[(size_t)(mat * 512 + n0 + nn2) * 512 + k0 + kk2] = lds[kk2][nn2];  // coalesced
    }
  } else {
    #pragma unroll
    for (int e = 0; e < 6; ++e) {
      int n = tid * 6 + e;
      const float* bsrc = (n < 512) ? bq : (n < 1024) ? bk : bv;
      bias[n] = bsrc[n & 511];
    }
  }
}

// ---- GEMM: A = x fp32 reg-staged->bf16 (native cvt); coalesced epilogue ----
// blocks 0..1023:    kv[16384][1024] = x @ [Wk|Wv]^T + b
// blocks 1024..1151: qc[4040][512]   = gather(x) @ Wq^T + bq
__global__ __launch_bounds__(256, 2) void gemm_kernel(
    const float* __restrict__ xf, const ushort* __restrict__ wt,
    const float* __restrict__ bias, ushort* __restrict__ kv, ushort* __restrict__ qc) {
  __shared__ char smem[33792];            // As 16K | Bs 16K ; epilogue [128][132]
  ushort* const As = (ushort*)smem;
  ushort* const Bs = (ushort*)(smem + 16384);

  const int tid = threadIdx.x;
  const int lane = tid & 63;
  const int wv = tid >> 6;
  const int bid = blockIdx.x;

  int m0, n0, ost, gather, mlim;
  const ushort* wtb;
  const float* biasb;
  ushort* outp;
  if (bid < 1024) {                       // kv partition, XCD swizzle within
    int swz = (bid & 7) * 128 + (bid >> 3);
    m0 = (swz >> 3) * 128; n0 = (swz & 7) * 128;
    wtb = wt + (size_t)512 * KDIM; biasb = bias + 512;
    outp = kv; ost = 1024; gather = 0; mlim = MROWS;
  } else {                                // q partition, XCD swizzle within
    int b2 = bid - 1024;
    int swz = (b2 & 7) * 16 + (b2 >> 3);
    m0 = (swz >> 2) * 128; n0 = (swz & 3) * 128;
    wtb = wt; biasb = bias;
    outp = qc; ost = 512; gather = 1; mlim = QROWS;
  }

  // staging: A from x fp32 (reg-stage->bf16, swizzled ds_write);
  //          B via global_load_lds (linear dest, inverse-swizzled source col)
  const float* aF[4];
  uint aDst[4];
  const ushort* bS[4];
  #pragma unroll
  for (int i = 0; i < 4; ++i) {
    int idx = i * 4096 + tid * 16;        // linear byte off in 16 KB tile
    int row = idx >> 7;                   // 128 B per tile row
    int colb = idx & 127;
    aDst[i] = (uint)(row * 128 + (colb ^ ((row & 7) << 4)));
    int scol = (colb ^ ((row & 7) << 4)) >> 1;
    size_t arow;
    if (gather) {
      int r = m0 + row;
      if (r > QROWS - 1) r = QROWS - 1;
      int bb = r / TOUT;
      int t2 = r - bb * TOUT;
      arow = (size_t)bb * TT + (size_t)t2 * 4 + FLT / 2;
    } else {
      arow = (size_t)(m0 + row);
    }
    aF[i] = xf + arow * KDIM + (colb >> 1);     // fp32 source, linear col
    bS[i] = wtb + (size_t)(n0 + row) * KDIM + scol;
  }

  const int fr = lane & 15;
  const int fq = lane >> 4;
  const int wr = wv >> 1;
  const int wc = wv & 1;

  f32x4 acc[4][4];
  #pragma unroll
  for (int i = 0; i < 4; ++i)
    #pragma unroll
    for (int j = 0; j < 4; ++j) acc[i][j] = (f32x4){0.f, 0.f, 0.f, 0.f};

  for (int t = 0; t < NT; ++t) {
    __syncthreads();
    const int koff = t * BK;
    #pragma unroll
    for (int i = 0; i < 4; ++i) {
      __builtin_amdgcn_global_load_lds(
          (const __attribute__((address_space(1))) unsigned int*)(bS[i] + koff),
          (__attribute__((address_space(3))) unsigned int*)((char*)Bs + i * 4096 + tid * 16),
          16, 0, 0);
    }
    #pragma unroll
    for (int i = 0; i < 4; ++i) {
      float4 lo = *reinterpret_cast<const float4*>(aF[i] + koff);
      float4 hi = *reinterpret_cast<const float4*>(aF[i] + koff + 4);
      *reinterpret_cast<bf16x8*>((char*)As + aDst[i]) = cvt8(lo, hi);
    }
    __syncthreads();

    #pragma unroll
    for (int ks = 0; ks < 2; ++ks) {
      bf16x8 af[4], bg[4];
      #pragma unroll
      for (int i = 0; i < 4; ++i) {
        int ra = wr * 64 + i * 16 + fr;
        int ca = ks * 64 + fq * 16;                 // byte col
        af[i] = *reinterpret_cast<const bf16x8*>(
            (const char*)As + ra * 128 + (ca ^ ((ra & 7) << 4)));
        int rb = wc * 64 + i * 16 + fr;
        bg[i] = *reinterpret_cast<const bf16x8*>(
            (const char*)Bs + rb * 128 + (ca ^ ((rb & 7) << 4)));
      }
      #pragma unroll
      for (int i = 0; i < 4; ++i)
        #pragma unroll
        for (int j = 0; j < 4; ++j)
          acc[i][j] = __builtin_amdgcn_mfma_f32_16x16x32_bf16(af[i], bg[j], acc[i][j], 0, 0, 0);
    }
  }

  // ---- epilogue: acc -> LDS bf16 [128][132] (native cvt) -> 16B stores ----
  __syncthreads();                        // K-loop LDS reads complete
  __bf16* const ep = (__bf16*)smem;
  #pragma unroll
  for (int j = 0; j < 4; ++j) {
    int colg = n0 + wc * 64 + j * 16 + fr;
    int coll = wc * 64 + j * 16 + fr;
    float bvl = biasb[colg];
    #pragma unroll
    for (int i = 0; i < 4; ++i) {
      int rowl = wr * 64 + i * 16 + fq * 4;
      #pragma unroll
      for (int r = 0; r < 4; ++r)
        ep[(rowl + r) * 132 + coll] = (__bf16)(acc[i][j][r] + bvl);
    }
  }
  __syncthreads();
  #pragma unroll
  for (int it = 0; it < 8; ++it) {
    int row = it * 16 + (tid >> 4);
    int gr = m0 + row;
    if (gr < mlim) {
      uint4 val = *reinterpret_cast<const uint4*>(&ep[row * 132 + (tid & 15) * 8]);
      *reinterpret_cast<uint4*>(outp + (size_t)gr * ost + n0 + (tid & 15) * 8) = val;
    }
  }
}

// ---------------- windowed attention (R2/R7-proven) ----------------
__global__ __launch_bounds__(256) void attn_kernel(
    const ushort* __restrict__ kv,   // [MROWS][1024] bf16: [k|v]
    const ushort* __restrict__ qc,   // [QROWS][512] bf16 (center q rows)
    float* __restrict__ out) {
  __shared__ float q_lds[KDIM];
  __shared__ float s_lds[FLT];
  __shared__ float p_lds[FLT];

  const int bid = blockIdx.x;
  const int b = bid & 7;                  // batch pinned to XCD (matches gemm)
  const int t = bid >> 3;
  const size_t base_row = (size_t)b * TT + (size_t)t * 4;
  const int tid = threadIdx.x;
  const int lane = tid & 63;
  const int wv = tid >> 6;

  {
    const ushort* qrow = qc + ((size_t)b * TOUT + t) * KDIM;
    uint v = *reinterpret_cast<const uint*>(qrow + tid * 2);
    q_lds[tid * 2]     = bf2f((ushort)(v & 0xffffu));
    q_lds[tid * 2 + 1] = bf2f((ushort)(v >> 16));
  }
  __syncthreads();

  // scores: 8 lanes per filter tap
  const int fl = lane >> 3;
  const int f = wv * 8 + fl;
  const int sub = lane & 7;
  const ushort* krow = kv + (base_row + f) * 1024;
  float acc = 0.f;
  #pragma unroll
  for (int j = 0; j < 8; ++j) {
    int d = (j * 8 + sub) * 8;
    uint4 kv4 = *reinterpret_cast<const uint4*>(krow + d);
    const ushort* ks = reinterpret_cast<const ushort*>(&kv4);
    #pragma unroll
    for (int e = 0; e < 8; ++e) acc += q_lds[d + e] * bf2f(ks[e]);
  }
  acc += __shfl_xor(acc, 1);
  acc += __shfl_xor(acc, 2);
  acc += __shfl_xor(acc, 4);
  if (sub == 0) s_lds[f] = acc * 0.04419417382415922f;  // 1/sqrt(512)
  __syncthreads();

  float m = -1e30f;
  #pragma unroll
  for (int i = 0; i < FLT; ++i) m = fmaxf(m, s_lds[i]);
  if (tid < FLT) p_lds[tid] = __expf(s_lds[tid] - m);
  __syncthreads();
  float sum = 0.f;
  #pragma unroll
  for (int i = 0; i < FLT; ++i) sum += p_lds[i];
  const float inv = 1.f / sum;

  const int d = tid * 2;
  float o0 = 0.f, o1 = 0.f;
  const ushort* vbase = kv + base_row * 1024 + 512 + d;
  #pragma unroll
  for (int ff = 0; ff < FLT; ++ff) {
    uint vvv = *reinterpret_cast<const uint*>(vbase + (size_t)ff * 1024);
    float w = p_lds[ff] * inv;
    o0 += w * bf2f((ushort)(vvv & 0xffffu));
    o1 += w * bf2f((ushort)(vvv >> 16));
  }
  float2* op = reinterpret_cast<float2*>(out + ((size_t)b * TOUT + t) * 512 + d);
  *op = make_float2(o0, o1);
}

// ---------------- launch ----------------
extern "C" void kernel_launch(void* const* d_in, const int* in_sizes, int n_in,
                              void* d_out, int out_size, void* d_ws, size_t ws_size,
                              hipStream_t stream) {
  const float* x  = (const float*)d_in[0];
  const float* Wq = (const float*)d_in[1];
  const float* bq = (const float*)d_in[2];
  const float* Wk = (const float*)d_in[3];
  const float* bk = (const float*)d_in[4];
  const float* Wv = (const float*)d_in[5];
  const float* bv = (const float*)d_in[6];
  float* out = (float*)d_out;

  char* ws = (char*)d_ws;
  ushort* wt   = (ushort*)ws;                        // 1.5 MiB
  float*  bias = (float*)(ws + 1572864);             // 8 KiB
  ushort* kvb  = (ushort*)(ws + 1581056);            // 32 MiB
  ushort* qc   = (ushort*)(ws + 1581056 + 33554432); // 4 MiB

  hipLaunchKernelGGL(wprep_kernel, dim3(193), dim3(256), 0, stream,
                     Wq, Wk, Wv, bq, bk, bv, wt, bias);
  hipLaunchKernelGGL(gemm_kernel, dim3(1152), dim3(256), 0, stream,
                     x, wt, bias, kvb, qc);
  hipLaunchKernelGGL(attn_kernel, dim3(QROWS), dim3(256), 0, stream, kvb, qc, out);
}

// Round 19
// 59.911 us; speedup vs baseline: 1.0913x; 1.0913x over previous
//
#include <hip/hip_runtime.h>
#include <hip/hip_bf16.h>
#include <cstdint>

#define FLT 32
#define TOUT 505
#define TT 2048
#define MROWS 16384
#define QROWS 4040                 // 8*505
#define KDIM 512
#define BK 64
#define NT 8                       // KDIM/BK

typedef float f32x4 __attribute__((ext_vector_type(4)));
typedef __bf16 bf16x8 __attribute__((ext_vector_type(8)));

static __device__ __forceinline__ ushort f2bf(float f) {
  uint32_t u = __float_as_uint(f);
  uint32_t r = (u + 0x7fffu + ((u >> 16) & 1u)) >> 16;
  return (ushort)r;
}
static __device__ __forceinline__ float bf2f(ushort h) {
  return __uint_as_float(((uint32_t)h) << 16);
}
static __device__ __forceinline__ void pack8(const float4& lo, const float4& hi, ushort* v8) {
  v8[0] = f2bf(lo.x); v8[1] = f2bf(lo.y); v8[2] = f2bf(lo.z); v8[3] = f2bf(lo.w);
  v8[4] = f2bf(hi.x); v8[5] = f2bf(hi.y); v8[6] = f2bf(hi.z); v8[7] = f2bf(hi.w);
}

// ---- wprep: W transposes (192 blocks) + bias gather (1 block). No x pass. --
__global__ void wprep_kernel(const float* __restrict__ Wq, const float* __restrict__ Wk,
                             const float* __restrict__ Wv, const float* __restrict__ bq,
                             const float* __restrict__ bk, const float* __restrict__ bv,
                             ushort* __restrict__ wt, float* __restrict__ bias) {
  const int bid = blockIdx.x;
  const int tid = threadIdx.x;
  if (bid < 192) {                        // 64x64 transpose tiles, 3 matrices
    __shared__ ushort lds[64][66];        // 132B stride: conflict-free
    int mat = bid >> 6;                   // 0 Wq, 1 Wk, 2 Wv
    int w = bid & 63;
    int k0 = (w >> 3) * 64, n0 = (w & 7) * 64;
    const float* W = (mat == 0) ? Wq : (mat == 1) ? Wk : Wv;
    int nn = tid & 63;
    #pragma unroll
    for (int r = 0; r < 16; ++r) {
      int kk = r * 4 + (tid >> 6);
      lds[kk][nn] = f2bf(W[(size_t)(k0 + kk) * 512 + n0 + nn]);   // coalesced
    }
    __syncthreads();
    int kk2 = tid & 63;
    #pragma unroll
    for (int r = 0; r < 16; ++r) {
      int nn2 = r * 4 + (tid >> 6);
      wt[(size_t)(mat * 512 + n0 + nn2) * 512 + k0 + kk2] = lds[kk2][nn2];  // coalesced
    }
  } else {
    #pragma unroll
    for (int e = 0; e < 6; ++e) {
      int n = tid * 6 + e;
      const float* bsrc = (n < 512) ? bq : (n < 1024) ? bk : bv;
      bias[n] = bsrc[n & 511];
    }
  }
}

// ---- GEMM: A = x fp32 reg-staged->bf16; coalesced LDS-staged epilogue ------
// blocks 0..1023:    kv[16384][1024] = x @ [Wk|Wv]^T + b
// blocks 1024..1151: qc[4040][512]   = gather(x) @ Wq^T + bq
__global__ __launch_bounds__(256, 2) void gemm_kernel(
    const float* __restrict__ xf, const ushort* __restrict__ wt,
    const float* __restrict__ bias, ushort* __restrict__ kv, ushort* __restrict__ qc) {
  __shared__ char smem[33792];            // As 16K | Bs 16K ; epilogue [128][132]
  ushort* const As = (ushort*)smem;
  ushort* const Bs = (ushort*)(smem + 16384);

  const int tid = threadIdx.x;
  const int lane = tid & 63;
  const int wv = tid >> 6;
  const int bid = blockIdx.x;

  int m0, n0, ost, gather, mlim;
  const ushort* wtb;
  const float* biasb;
  ushort* outp;
  if (bid < 1024) {                       // kv partition, XCD swizzle within
    int swz = (bid & 7) * 128 + (bid >> 3);
    m0 = (swz >> 3) * 128; n0 = (swz & 7) * 128;
    wtb = wt + (size_t)512 * KDIM; biasb = bias + 512;
    outp = kv; ost = 1024; gather = 0; mlim = MROWS;
  } else {                                // q partition, XCD swizzle within
    int b2 = bid - 1024;
    int swz = (b2 & 7) * 16 + (b2 >> 3);
    m0 = (swz >> 2) * 128; n0 = (swz & 3) * 128;
    wtb = wt; biasb = bias;
    outp = qc; ost = 512; gather = 1; mlim = QROWS;
  }

  // staging: A from x fp32 (reg-stage->bf16, swizzled ds_write);
  //          B via global_load_lds (linear dest, inverse-swizzled source col)
  const float* aF[4];
  uint aDst[4];
  const ushort* bS[4];
  #pragma unroll
  for (int i = 0; i < 4; ++i) {
    int idx = i * 4096 + tid * 16;        // linear byte off in 16 KB tile
    int row = idx >> 7;                   // 128 B per tile row
    int colb = idx & 127;
    aDst[i] = (uint)(row * 128 + (colb ^ ((row & 7) << 4)));
    int scol = (colb ^ ((row & 7) << 4)) >> 1;
    size_t arow;
    if (gather) {
      int r = m0 + row;
      if (r > QROWS - 1) r = QROWS - 1;
      int bb = r / TOUT;
      int t2 = r - bb * TOUT;
      arow = (size_t)bb * TT + (size_t)t2 * 4 + FLT / 2;
    } else {
      arow = (size_t)(m0 + row);
    }
    aF[i] = xf + arow * KDIM + (colb >> 1);     // fp32 source, linear col
    bS[i] = wtb + (size_t)(n0 + row) * KDIM + scol;
  }

  const int fr = lane & 15;
  const int fq = lane >> 4;
  const int wr = wv >> 1;
  const int wc = wv & 1;

  f32x4 acc[4][4];
  #pragma unroll
  for (int i = 0; i < 4; ++i)
    #pragma unroll
    for (int j = 0; j < 4; ++j) acc[i][j] = (f32x4){0.f, 0.f, 0.f, 0.f};

  for (int t = 0; t < NT; ++t) {
    __syncthreads();
    const int koff = t * BK;
    #pragma unroll
    for (int i = 0; i < 4; ++i) {
      __builtin_amdgcn_global_load_lds(
          (const __attribute__((address_space(1))) unsigned int*)(bS[i] + koff),
          (__attribute__((address_space(3))) unsigned int*)((char*)Bs + i * 4096 + tid * 16),
          16, 0, 0);
    }
    #pragma unroll
    for (int i = 0; i < 4; ++i) {
      float4 lo = *reinterpret_cast<const float4*>(aF[i] + koff);
      float4 hi = *reinterpret_cast<const float4*>(aF[i] + koff + 4);
      ushort v8[8]; pack8(lo, hi, v8);
      *reinterpret_cast<uint4*>((char*)As + aDst[i]) = *reinterpret_cast<const uint4*>(v8);
    }
    __syncthreads();

    #pragma unroll
    for (int ks = 0; ks < 2; ++ks) {
      bf16x8 af[4], bg[4];
      #pragma unroll
      for (int i = 0; i < 4; ++i) {
        int ra = wr * 64 + i * 16 + fr;
        int ca = ks * 64 + fq * 16;                 // byte col
        af[i] = *reinterpret_cast<const bf16x8*>(
            (const char*)As + ra * 128 + (ca ^ ((ra & 7) << 4)));
        int rb = wc * 64 + i * 16 + fr;
        bg[i] = *reinterpret_cast<const bf16x8*>(
            (const char*)Bs + rb * 128 + (ca ^ ((rb & 7) << 4)));
      }
      #pragma unroll
      for (int i = 0; i < 4; ++i)
        #pragma unroll
        for (int j = 0; j < 4; ++j)
          acc[i][j] = __builtin_amdgcn_mfma_f32_16x16x32_bf16(af[i], bg[j], acc[i][j], 0, 0, 0);
    }
  }

  // ---- epilogue: acc -> LDS bf16 [128][132] -> coalesced 16B stores ----
  __syncthreads();                        // K-loop LDS reads complete
  ushort* const ep = (ushort*)smem;
  #pragma unroll
  for (int j = 0; j < 4; ++j) {
    int colg = n0 + wc * 64 + j * 16 + fr;
    int coll = wc * 64 + j * 16 + fr;
    float bvl = biasb[colg];
    #pragma unroll
    for (int i = 0; i < 4; ++i) {
      int rowl = wr * 64 + i * 16 + fq * 4;
      #pragma unroll
      for (int r = 0; r < 4; ++r)
        ep[(rowl + r) * 132 + coll] = f2bf(acc[i][j][r] + bvl);
    }
  }
  __syncthreads();
  #pragma unroll
  for (int it = 0; it < 8; ++it) {
    int row = it * 16 + (tid >> 4);
    int gr = m0 + row;
    if (gr < mlim) {
      uint4 val = *reinterpret_cast<const uint4*>(&ep[row * 132 + (tid & 15) * 8]);
      *reinterpret_cast<uint4*>(outp + (size_t)gr * ost + n0 + (tid & 15) * 8) = val;
    }
  }
}

// ---------------- windowed attention (R2/R7-proven) ----------------
__global__ __launch_bounds__(256) void attn_kernel(
    const ushort* __restrict__ kv,   // [MROWS][1024] bf16: [k|v]
    const ushort* __restrict__ qc,   // [QROWS][512] bf16 (center q rows)
    float* __restrict__ out) {
  __shared__ float q_lds[KDIM];
  __shared__ float s_lds[FLT];
  __shared__ float p_lds[FLT];

  const int bid = blockIdx.x;
  const int b = bid & 7;                  // batch pinned to XCD (matches gemm)
  const int t = bid >> 3;
  const size_t base_row = (size_t)b * TT + (size_t)t * 4;
  const int tid = threadIdx.x;
  const int lane = tid & 63;
  const int wv = tid >> 6;

  {
    const ushort* qrow = qc + ((size_t)b * TOUT + t) * KDIM;
    uint v = *reinterpret_cast<const uint*>(qrow + tid * 2);
    q_lds[tid * 2]     = bf2f((ushort)(v & 0xffffu));
    q_lds[tid * 2 + 1] = bf2f((ushort)(v >> 16));
  }
  __syncthreads();

  // scores: 8 lanes per filter tap
  const int fl = lane >> 3;
  const int f = wv * 8 + fl;
  const int sub = lane & 7;
  const ushort* krow = kv + (base_row + f) * 1024;
  float acc = 0.f;
  #pragma unroll
  for (int j = 0; j < 8; ++j) {
    int d = (j * 8 + sub) * 8;
    uint4 kv4 = *reinterpret_cast<const uint4*>(krow + d);
    const ushort* ks = reinterpret_cast<const ushort*>(&kv4);
    #pragma unroll
    for (int e = 0; e < 8; ++e) acc += q_lds[d + e] * bf2f(ks[e]);
  }
  acc += __shfl_xor(acc, 1);
  acc += __shfl_xor(acc, 2);
  acc += __shfl_xor(acc, 4);
  if (sub == 0) s_lds[f] = acc * 0.04419417382415922f;  // 1/sqrt(512)
  __syncthreads();

  float m = -1e30f;
  #pragma unroll
  for (int i = 0; i < FLT; ++i) m = fmaxf(m, s_lds[i]);
  if (tid < FLT) p_lds[tid] = __expf(s_lds[tid] - m);
  __syncthreads();
  float sum = 0.f;
  #pragma unroll
  for (int i = 0; i < FLT; ++i) sum += p_lds[i];
  const float inv = 1.f / sum;

  const int d = tid * 2;
  float o0 = 0.f, o1 = 0.f;
  const ushort* vbase = kv + base_row * 1024 + 512 + d;
  #pragma unroll
  for (int ff = 0; ff < FLT; ++ff) {
    uint vvv = *reinterpret_cast<const uint*>(vbase + (size_t)ff * 1024);
    float w = p_lds[ff] * inv;
    o0 += w * bf2f((ushort)(vvv & 0xffffu));
    o1 += w * bf2f((ushort)(vvv >> 16));
  }
  float2* op = reinterpret_cast<float2*>(out + ((size_t)b * TOUT + t) * 512 + d);
  *op = make_float2(o0, o1);
}

// ---------------- launch ----------------
extern "C" void kernel_launch(void* const* d_in, const int* in_sizes, int n_in,
                              void* d_out, int out_size, void* d_ws, size_t ws_size,
                              hipStream_t stream) {
  const float* x  = (const float*)d_in[0];
  const float* Wq = (const float*)d_in[1];
  const float* bq = (const float*)d_in[2];
  const float* Wk = (const float*)d_in[3];
  const float* bk = (const float*)d_in[4];
  const float* Wv = (const float*)d_in[5];
  const float* bv = (const float*)d_in[6];
  float* out = (float*)d_out;

  char* ws = (char*)d_ws;
  ushort* wt   = (ushort*)ws;                        // 1.5 MiB
  float*  bias = (float*)(ws + 1572864);             // 8 KiB
  ushort* kvb  = (ushort*)(ws + 1581056);            // 32 MiB
  ushort* qc   = (ushort*)(ws + 1581056 + 33554432); // 4 MiB

  hipLaunchKernelGGL(wprep_kernel, dim3(193), dim3(256), 0, stream,
                     Wq, Wk, Wv, bq, bk, bv, wt, bias);
  hipLaunchKernelGGL(gemm_kernel, dim3(1152), dim3(256), 0, stream,
                     x, wt, bias, kvb, qc);
  hipLaunchKernelGGL(attn_kernel, dim3(QROWS), dim3(256), 0, stream, kvb, qc, out);
}